// Round 1
// baseline (229.565 us; speedup 1.0000x reference)
//
#include <hip/hip_runtime.h>

// Sigma = Q diag(exp(2*log_s)) Q^T for N quaternions.
// Memory-bound: 64 B/point (28 in + 36 out). Traffic floor 256 MB ~= 40 us.
// R3: thread-coarsen x2 (512 pts/block). Halves per-point barrier + block-churn
//     overhead, doubles per-thread MLP. q loads hoisted above the staging
//     barriers so HBM latency hides under stage+sync.
// LDS 18432 B/block -> 8 blocks/CU (147 KB < 160 KB), 32 waves/CU: full occupancy.

#define BLOCK 256
#define PPT   2
#define PTS   (BLOCK * PPT)   // 512 points per block

__device__ __forceinline__ void sigma_from_point(
    float4 qv, float l0, float l1, float l2, float* __restrict__ row)
{
    float w = qv.x, x = qv.y, y = qv.z, z = qv.w;
    float nrm2 = w*w + x*x + y*y + z*z;
    float inv = __builtin_amdgcn_rsqf(nrm2);     // v_rsq_f32
    w *= inv; x *= inv; y *= inv; z *= inv;

    float xx = x*x, yy = y*y, zz = z*z;
    float xy = x*y, xz = x*z, yz = y*z;
    float wx = w*x, wy = w*y, wz = w*z;

    float r00 = 1.0f - 2.0f*(yy + zz);
    float r01 = 2.0f*(xy - wz);
    float r02 = 2.0f*(xz + wy);
    float r10 = 2.0f*(xy + wz);
    float r11 = 1.0f - 2.0f*(xx + zz);
    float r12 = 2.0f*(yz - wx);
    float r20 = 2.0f*(xz - wy);
    float r21 = 2.0f*(yz + wx);
    float r22 = 1.0f - 2.0f*(xx + yy);

    float s0 = __expf(2.0f * l0);                // v_exp_f32 path
    float s1 = __expf(2.0f * l1);
    float s2 = __expf(2.0f * l2);

    // Sigma[i][k] = sum_j R[i][j]*s[j]*R[k][j]  (symmetric)
    float a0 = r00*s0, a1 = r01*s1, a2 = r02*s2;
    float S00 = a0*r00 + a1*r01 + a2*r02;
    float S01 = a0*r10 + a1*r11 + a2*r12;
    float S02 = a0*r20 + a1*r21 + a2*r22;
    float b0 = r10*s0, b1 = r11*s1, b2 = r12*s2;
    float S11 = b0*r10 + b1*r11 + b2*r12;
    float S12 = b0*r20 + b1*r21 + b2*r22;
    float S22 = r20*r20*s0 + r21*r21*s1 + r22*r22*s2;

    row[0] = S00; row[1] = S01; row[2] = S02;
    row[3] = S01; row[4] = S11; row[5] = S12;
    row[6] = S02; row[7] = S12; row[8] = S22;
}

__global__ __launch_bounds__(BLOCK) void gaussian_sigma_kernel(
    const float4* __restrict__ q4,      // (N,4) as float4
    const float*  __restrict__ log_s,   // (N,3)
    float*        __restrict__ out,     // (N,9)
    int n)
{
    __shared__ float lds[PTS * 9];      // 18432 B: ls stage, then Sigma stage

    const int tid        = threadIdx.x;
    const int block_base = blockIdx.x * PTS;
    const bool full_block = (block_base + PTS) <= n;

    if (full_block) {
        const int i0 = block_base + tid;
        const int i1 = i0 + BLOCK;

        // issue q loads first: latency hides under ls staging + barriers
        float4 qa = q4[i0];
        float4 qb = q4[i1];

        // ---- stage log_s: PTS*3 floats = 384 float4, coalesced ----
        {
            const float4* ls4 = reinterpret_cast<const float4*>(log_s + (size_t)block_base * 3);
            float4* lds4 = reinterpret_cast<float4*>(lds);
            #pragma unroll
            for (int j = tid; j < PTS * 3 / 4; j += BLOCK)
                lds4[j] = ls4[j];
        }
        __syncthreads();
        // stride-3 words: gcd(3,32)=1 -> 2-way alias across 64 lanes, free
        float la0 = lds[tid*3 + 0], la1 = lds[tid*3 + 1], la2 = lds[tid*3 + 2];
        float lb0 = lds[(tid+BLOCK)*3 + 0], lb1 = lds[(tid+BLOCK)*3 + 1], lb2 = lds[(tid+BLOCK)*3 + 2];
        __syncthreads();    // all ls reads done before Sigma overwrites the buffer

        // ---- compute + stage Sigma (stride-9 words, odd -> 2-way alias, free) ----
        sigma_from_point(qa, la0, la1, la2, lds + tid * 9);
        sigma_from_point(qb, lb0, lb1, lb2, lds + (tid + BLOCK) * 9);
        __syncthreads();

        // ---- copy out: PTS*9/4 = 1152 float4, coalesced; base 16B-aligned ----
        float4* out4 = reinterpret_cast<float4*>(out + (size_t)block_base * 9);
        const float4* lds4 = reinterpret_cast<const float4*>(lds);
        #pragma unroll
        for (int j = tid; j < PTS * 9 / 4; j += BLOCK)
            out4[j] = lds4[j];
    } else {
        // ---- tail block (at most one, 256 of 4M points): scalar path ----
        #pragma unroll
        for (int p = 0; p < PPT; ++p) {
            const int i = block_base + tid + p * BLOCK;
            if (i < n) {
                float4 qv = q4[i];
                float l0 = log_s[(size_t)i*3 + 0];
                float l1 = log_s[(size_t)i*3 + 1];
                float l2 = log_s[(size_t)i*3 + 2];
                float row[9];
                sigma_from_point(qv, l0, l1, l2, row);
                float* o = out + (size_t)i * 9;
                #pragma unroll
                for (int c = 0; c < 9; ++c) o[c] = row[c];
            }
        }
    }
}

extern "C" void kernel_launch(void* const* d_in, const int* in_sizes, int n_in,
                              void* d_out, int out_size, void* d_ws, size_t ws_size,
                              hipStream_t stream) {
    const float4* q4    = (const float4*)d_in[0];   // (N,4) float32
    const float*  log_s = (const float*)d_in[1];    // (N,3) float32
    float*        out   = (float*)d_out;            // (N,3,3) float32

    const int n = in_sizes[0] / 4;                  // N points
    const int grid = (n + PTS - 1) / PTS;
    gaussian_sigma_kernel<<<grid, BLOCK, 0, stream>>>(q4, log_s, out, n);
}

// Round 4
// 215.004 us; speedup vs baseline: 1.0677x; 1.0677x over previous
//
#include <hip/hip_runtime.h>

// Sigma = Q diag(exp(2*log_s)) Q^T for N quaternions.
// Memory-bound: 64 B/point (28 in + 36 out) = 256 MB total, floor ~41 us.
// R6 == R5 (infra failure, resubmit): R2 structure (1 pt/thread, best measured
//     226us) + NONTEMPORAL global access.
//     All 256 MB is touched exactly once -> nt loads skip L2 pollution,
//     nt stores avoid read-for-ownership on the 144 MB output stream.
//     __builtin_nontemporal_* requires native clang vector types,
//     not HIP_vector_type<float,4> -> use ext_vector_type(4) for the accesses.

#define BLOCK 256

typedef float fx4 __attribute__((ext_vector_type(4)));   // native vector for nt builtins

__global__ __launch_bounds__(BLOCK) void gaussian_sigma_kernel(
    const float* __restrict__ q,        // (N,4)
    const float* __restrict__ log_s,    // (N,3)
    float*       __restrict__ out,      // (N,9)
    int n)
{
    __shared__ float lds[BLOCK * 9];    // 9216 B: reused for log_s stage then Sigma stage

    const int tid        = threadIdx.x;
    const int block_base = blockIdx.x * BLOCK;        // first point of this block
    const int i          = block_base + tid;
    const bool full_block = (block_base + BLOCK) <= n;

    // ---- stage log_s: BLOCK*3 floats = BLOCK*3/4 fx4 ----
    float l0, l1, l2;
    if (full_block) {
        const fx4* ls4 = reinterpret_cast<const fx4*>(log_s + (size_t)block_base * 3);
        fx4* lds4 = reinterpret_cast<fx4*>(lds);
        if (tid < BLOCK * 3 / 4)
            lds4[tid] = __builtin_nontemporal_load(&ls4[tid]);   // nt: no reuse
        __syncthreads();
        l0 = lds[tid * 3 + 0];   // stride-3 words: gcd(3,32)=1 -> 2-way alias, free
        l1 = lds[tid * 3 + 1];
        l2 = lds[tid * 3 + 2];
        __syncthreads();
    } else {
        if (i < n) {
            l0 = log_s[(size_t)i * 3 + 0];
            l1 = log_s[(size_t)i * 3 + 1];
            l2 = log_s[(size_t)i * 3 + 2];
        } else {
            l0 = l1 = l2 = 0.0f;
        }
    }

    // ---- per-point math ----
    float S00=0, S01=0, S02=0, S11=0, S12=0, S22=0;
    if (i < n) {
        const fx4* q4 = reinterpret_cast<const fx4*>(q);
        fx4 qv = __builtin_nontemporal_load(&q4[i]);             // nt: no reuse
        float w = qv.x, x = qv.y, y = qv.z, z = qv.w;
        float nrm2 = w*w + x*x + y*y + z*z;
        float inv = __builtin_amdgcn_rsqf(nrm2);     // v_rsq_f32
        w *= inv; x *= inv; y *= inv; z *= inv;

        float xx = x*x, yy = y*y, zz = z*z;
        float xy = x*y, xz = x*z, yz = y*z;
        float wx = w*x, wy = w*y, wz = w*z;

        float r00 = 1.0f - 2.0f*(yy + zz);
        float r01 = 2.0f*(xy - wz);
        float r02 = 2.0f*(xz + wy);
        float r10 = 2.0f*(xy + wz);
        float r11 = 1.0f - 2.0f*(xx + zz);
        float r12 = 2.0f*(yz - wx);
        float r20 = 2.0f*(xz - wy);
        float r21 = 2.0f*(yz + wx);
        float r22 = 1.0f - 2.0f*(xx + yy);

        float s0 = __expf(2.0f * l0);                // v_exp_f32 path
        float s1 = __expf(2.0f * l1);
        float s2 = __expf(2.0f * l2);

        // Sigma[i][k] = sum_j R[i][j]*s[j]*R[k][j]  (symmetric)
        float a0 = r00*s0, a1 = r01*s1, a2 = r02*s2;
        S00 = a0*r00 + a1*r01 + a2*r02;
        S01 = a0*r10 + a1*r11 + a2*r12;
        S02 = a0*r20 + a1*r21 + a2*r22;
        float b0 = r10*s0, b1 = r11*s1, b2 = r12*s2;
        S11 = b0*r10 + b1*r11 + b2*r12;
        S12 = b0*r20 + b1*r21 + b2*r22;
        S22 = r20*r20*s0 + r21*r21*s1 + r22*r22*s2;
    }

    // ---- write Sigma ----
    if (full_block) {
        // stage 9 floats/thread in LDS (stride 9 words, odd -> <=2-way bank alias, free)
        float* row = lds + tid * 9;
        row[0] = S00; row[1] = S01; row[2] = S02;
        row[3] = S01; row[4] = S11; row[5] = S12;
        row[6] = S02; row[7] = S12; row[8] = S22;
        __syncthreads();
        // block output byte base = blockIdx*BLOCK*36 = 9216*blockIdx -> 16B aligned
        fx4* out4 = reinterpret_cast<fx4*>(out + (size_t)block_base * 9);
        const fx4* lds4 = reinterpret_cast<const fx4*>(lds);
        #pragma unroll
        for (int j = tid; j < BLOCK * 9 / 4; j += BLOCK)
            __builtin_nontemporal_store(lds4[j], &out4[j]);      // nt: streaming store
    } else if (i < n) {
        float* o = out + (size_t)i * 9;
        o[0] = S00; o[1] = S01; o[2] = S02;
        o[3] = S01; o[4] = S11; o[5] = S12;
        o[6] = S02; o[7] = S12; o[8] = S22;
    }
}

extern "C" void kernel_launch(void* const* d_in, const int* in_sizes, int n_in,
                              void* d_out, int out_size, void* d_ws, size_t ws_size,
                              hipStream_t stream) {
    const float* q     = (const float*)d_in[0];     // (N,4) float32
    const float* log_s = (const float*)d_in[1];     // (N,3) float32
    float*       out   = (float*)d_out;             // (N,3,3) float32

    const int n = in_sizes[0] / 4;                  // N points
    const int grid = (n + BLOCK - 1) / BLOCK;
    gaussian_sigma_kernel<<<grid, BLOCK, 0, stream>>>(q, log_s, out, n);
}